// Round 4
// baseline (399.566 us; speedup 1.0000x reference)
//
#include <hip/hip_runtime.h>
#include <hip/hip_bf16.h>

typedef unsigned short ushort_t;
typedef __attribute__((ext_vector_type(8))) short short8;
typedef __attribute__((ext_vector_type(4))) float f32x4;

#define M_DIM 8192
#define N_DIM 8192
#define K_DIM 2048
#define BM 256
#define BN 256
#define BK 32
#define NT (K_DIM / BK)        // 64 K-tiles
#define SLOT_ELEMS (BM * BK)   // 8192 bf16 = 16 KiB per operand slot

__device__ __forceinline__ ushort_t f2bf(float f) {
    union { float f; unsigned u; } v; v.f = f;
    unsigned r = v.u + 0x7fffu + ((v.u >> 16) & 1u);   // RNE
    return (ushort_t)(r >> 16);
}

__device__ __forceinline__ void async_copy16(const void* g, void* l) {
    __builtin_amdgcn_global_load_lds(
        (const __attribute__((address_space(1))) void*)g,
        (__attribute__((address_space(3))) void*)l, 16, 0, 0);
}

// ---- kernel 1: x (f32) -> A (bf16) ----
__global__ __launch_bounds__(256) void convert_x(const float* __restrict__ x,
                                                 ushort_t* __restrict__ A) {
    int t = blockIdx.x * 256 + threadIdx.x;
    const float4* p = (const float4*)x + (size_t)t * 2;
    float4 a = p[0], b = p[1];
    short8 o;
    o[0] = (short)f2bf(a.x); o[1] = (short)f2bf(a.y);
    o[2] = (short)f2bf(a.z); o[3] = (short)f2bf(a.w);
    o[4] = (short)f2bf(b.x); o[5] = (short)f2bf(b.y);
    o[6] = (short)f2bf(b.z); o[7] = (short)f2bf(b.w);
    *(short8*)(A + (size_t)t * 8) = o;
}

// ---- kernel 2: codebook gather -> Bt (bf16, N x K layout) ----
__global__ __launch_bounds__(256) void dequant_wt(const int* __restrict__ indices,
                                                  const float* __restrict__ codebook,
                                                  ushort_t* __restrict__ Bt) {
    int g = blockIdx.x;                       // column group 0..1023
    int i = blockIdx.y * 256 + threadIdx.x;   // K row 0..2047
    int idx = indices[(size_t)i * 1024 + g];
    const float4* cb = (const float4*)(codebook + (size_t)idx * 8);
    float4 lo = cb[0], hi = cb[1];
    size_t base = (size_t)g * 8 * K_DIM + i;
    Bt[base + 0 * K_DIM] = f2bf(lo.x);
    Bt[base + 1 * K_DIM] = f2bf(lo.y);
    Bt[base + 2 * K_DIM] = f2bf(lo.z);
    Bt[base + 3 * K_DIM] = f2bf(lo.w);
    Bt[base + 4 * K_DIM] = f2bf(hi.x);
    Bt[base + 5 * K_DIM] = f2bf(hi.y);
    Bt[base + 6 * K_DIM] = f2bf(hi.z);
    Bt[base + 7 * K_DIM] = f2bf(hi.w);
}

// ---- kernel 3: C = A(MxK) * Bt(NxK)^T + bias ----
// 256x256 tile, BK=32, 4-deep LDS K-tile pipeline, 1 barrier/tile.
__global__ __launch_bounds__(512, 2) void gemm_256_pipe(const ushort_t* __restrict__ A,
                                                        const ushort_t* __restrict__ Bt,
                                                        const float* __restrict__ bias,
                                                        float* __restrict__ C) {
    __shared__ __align__(16) ushort_t lds_a[4][SLOT_ELEMS];   // 64 KiB
    __shared__ __align__(16) ushort_t lds_b[4][SLOT_ELEMS];   // 64 KiB

    const int bid = blockIdx.x;                      // 1024 blocks (32x32 tiles)
    const int swz = (bid & 7) * 128 + (bid >> 3);    // XCD swizzle (1024 % 8 == 0)
    const int m0 = (swz >> 5) * BM;
    const int n0 = (swz & 31) * BN;

    const int tid = threadIdx.x;
    const int lane = tid & 63;
    const int wid = tid >> 6;              // 0..7
    const int wm = wid >> 2, wn = wid & 3; // 2 x 4 wave grid; wave out = 128x64
    const int lane15 = lane & 15, laneq = lane >> 4;

    // --- staging: linear LDS granule G -> inverse-swizzled global k-granule ---
    // LDS[row][c'] holds global (row, c = c' ^ ((row>>1)&3)); row = G>>2, c' = G&3.
    const int r0 = tid >> 2;                 // rows 0..127 (G0 = tid)
    const int r1 = r0 + 128;                 // rows 128..255 (G1 = 512+tid)
    const int c0g = (tid & 3) ^ ((r0 >> 1) & 3);
    const int c1g = (tid & 3) ^ ((r1 >> 1) & 3);
    const size_t aO0 = (size_t)(m0 + r0) * K_DIM + c0g * 8;
    const size_t aO1 = (size_t)(m0 + r1) * K_DIM + c1g * 8;
    const size_t bO0 = (size_t)(n0 + r0) * K_DIM + c0g * 8;
    const size_t bO1 = (size_t)(n0 + r1) * K_DIM + c1g * 8;
    const int dq0 = tid * 16, dq1 = tid * 16 + 8192;

#define STAGE(gt) do { int _sl = (gt) & 3; \
        async_copy16(A  + aO0 + (size_t)(gt) * BK, (char*)&lds_a[_sl][0] + dq0); \
        async_copy16(A  + aO1 + (size_t)(gt) * BK, (char*)&lds_a[_sl][0] + dq1); \
        async_copy16(Bt + bO0 + (size_t)(gt) * BK, (char*)&lds_b[_sl][0] + dq0); \
        async_copy16(Bt + bO1 + (size_t)(gt) * BK, (char*)&lds_b[_sl][0] + dq1); \
    } while (0)

    // --- swizzled ds_read byte offsets within a slot (row stride 64 B) ---
    int offA[8], offB[4];
#pragma unroll
    for (int i = 0; i < 8; ++i) {
        int row = wm * 128 + i * 16 + lane15;
        offA[i] = row * 64 + ((laneq ^ ((row >> 1) & 3)) << 4);
    }
#pragma unroll
    for (int j = 0; j < 4; ++j) {
        int row = wn * 64 + j * 16 + lane15;
        offB[j] = row * 64 + ((laneq ^ ((row >> 1) & 3)) << 4);
    }

    f32x4 acc[8][4];
#pragma unroll
    for (int i = 0; i < 8; ++i)
#pragma unroll
        for (int j = 0; j < 4; ++j) acc[i][j] = (f32x4){0.f, 0.f, 0.f, 0.f};

    // --- prologue: 3 tiles in flight ---
    STAGE(0); STAGE(1); STAGE(2);

    short8 af[8], bf[4];

    for (int g = 0; g < NT; ++g) {
        // tile g landed (drain own 4 oldest stage loads), then sync all waves
        if (g < NT - 2)       { asm volatile("s_waitcnt vmcnt(8)" ::: "memory"); }
        else if (g == NT - 2) { asm volatile("s_waitcnt vmcnt(4)" ::: "memory"); }
        else                  { asm volatile("s_waitcnt vmcnt(0)" ::: "memory"); }
        __builtin_amdgcn_s_barrier();   // also fences: everyone done reading slot (g+3)&3

        if (g + 3 < NT) STAGE(g + 3);

        const char* sa = (const char*)&lds_a[g & 3][0];
        const char* sb = (const char*)&lds_b[g & 3][0];
        // batch 1: 8 reads (af[0..3], bf[0..3])
#pragma unroll
        for (int i = 0; i < 4; ++i) af[i] = *(const short8*)(sa + offA[i]);
#pragma unroll
        for (int j = 0; j < 4; ++j) bf[j] = *(const short8*)(sb + offB[j]);
        asm volatile("" ::: "memory");
        __builtin_amdgcn_sched_barrier(0);
        // batch 2: 4 reads (af[4..7]) — land during cluster 1
#pragma unroll
        for (int i = 4; i < 8; ++i) af[i] = *(const short8*)(sa + offA[i]);

        asm volatile("s_waitcnt lgkmcnt(4)" ::: "memory");   // batch 1 done
        __builtin_amdgcn_sched_barrier(0);
        __builtin_amdgcn_s_setprio(1);
#pragma unroll
        for (int i = 0; i < 4; ++i)
#pragma unroll
            for (int j = 0; j < 4; ++j)
                acc[i][j] = __builtin_amdgcn_mfma_f32_16x16x32_bf16(af[i], bf[j], acc[i][j], 0, 0, 0);
        __builtin_amdgcn_s_setprio(0);

        asm volatile("s_waitcnt lgkmcnt(0)" ::: "memory");   // batch 2 done
        __builtin_amdgcn_sched_barrier(0);
        __builtin_amdgcn_s_setprio(1);
#pragma unroll
        for (int i = 4; i < 8; ++i)
#pragma unroll
            for (int j = 0; j < 4; ++j)
                acc[i][j] = __builtin_amdgcn_mfma_f32_16x16x32_bf16(af[i], bf[j], acc[i][j], 0, 0, 0);
        __builtin_amdgcn_s_setprio(0);
    }

    // --- epilogue: bias + f32 store ---
    // acc[i][j]: row = m0 + wm*128 + i*16 + laneq*4 + q ; col = n0 + wn*64 + j*16 + lane15
#pragma unroll
    for (int i = 0; i < 8; ++i) {
        int row = m0 + wm * 128 + i * 16 + laneq * 4;
#pragma unroll
        for (int j = 0; j < 4; ++j) {
            int col = n0 + wn * 64 + j * 16 + lane15;
            float bv = bias[col];
            f32x4 v = acc[i][j];
#pragma unroll
            for (int q = 0; q < 4; ++q)
                C[(size_t)(row + q) * N_DIM + col] = v[q] + bv;
        }
    }
#undef STAGE
}

extern "C" void kernel_launch(void* const* d_in, const int* in_sizes, int n_in,
                              void* d_out, int out_size, void* d_ws, size_t ws_size,
                              hipStream_t stream) {
    const float* x = (const float*)d_in[0];
    const float* codebook = (const float*)d_in[1];
    const int* indices = (const int*)d_in[2];      // harness: integer -> int32
    const float* bias = (const float*)d_in[3];
    float* out = (float*)d_out;

    ushort_t* A  = (ushort_t*)d_ws;                               // 32 MB
    ushort_t* Bt = (ushort_t*)d_ws + (size_t)M_DIM * K_DIM;       // 32 MB

    convert_x<<<dim3(M_DIM * K_DIM / (256 * 8)), 256, 0, stream>>>(x, A);
    dequant_wt<<<dim3(1024, 8), 256, 0, stream>>>(indices, codebook, Bt);
    gemm_256_pipe<<<dim3((M_DIM / BM) * (N_DIM / BN)), 512, 0, stream>>>(A, Bt, bias, out);
}

// Round 5
// 329.743 us; speedup vs baseline: 1.2117x; 1.2117x over previous
//
#include <hip/hip_runtime.h>
#include <hip/hip_bf16.h>

typedef unsigned short ushort_t;
typedef __attribute__((ext_vector_type(8))) short short8;
typedef __attribute__((ext_vector_type(4))) float f32x4;

#define M_DIM 8192
#define N_DIM 8192
#define K_DIM 2048
#define BM 256
#define BN 256
#define BK 64
#define NT (K_DIM / BK)   // 32 K-tiles

__device__ __forceinline__ ushort_t f2bf(float f) {
    union { float f; unsigned u; } v; v.f = f;
    unsigned r = v.u + 0x7fffu + ((v.u >> 16) & 1u);   // RNE
    return (ushort_t)(r >> 16);
}

__device__ __forceinline__ void async_copy16(const void* g, void* l) {
    __builtin_amdgcn_global_load_lds(
        (const __attribute__((address_space(1))) void*)g,
        (__attribute__((address_space(3))) void*)l, 16, 0, 0);
}

#define BAR() __builtin_amdgcn_s_barrier()
#define LGKM0() do { asm volatile("s_waitcnt lgkmcnt(0)" ::: "memory"); \
                     __builtin_amdgcn_sched_barrier(0); } while (0)

// ---- kernel 1: x (f32) -> A (bf16) ----
__global__ __launch_bounds__(256) void convert_x(const float* __restrict__ x,
                                                 ushort_t* __restrict__ A) {
    int t = blockIdx.x * 256 + threadIdx.x;
    const float4* p = (const float4*)x + (size_t)t * 2;
    float4 a = p[0], b = p[1];
    short8 o;
    o[0] = (short)f2bf(a.x); o[1] = (short)f2bf(a.y);
    o[2] = (short)f2bf(a.z); o[3] = (short)f2bf(a.w);
    o[4] = (short)f2bf(b.x); o[5] = (short)f2bf(b.y);
    o[6] = (short)f2bf(b.z); o[7] = (short)f2bf(b.w);
    *(short8*)(A + (size_t)t * 8) = o;
}

// ---- kernel 2: codebook gather -> Bt (bf16, N x K layout) ----
__global__ __launch_bounds__(256) void dequant_wt(const int* __restrict__ indices,
                                                  const float* __restrict__ codebook,
                                                  ushort_t* __restrict__ Bt) {
    int g = blockIdx.x;                       // column group 0..1023
    int i = blockIdx.y * 256 + threadIdx.x;   // K row 0..2047
    int idx = indices[(size_t)i * 1024 + g];
    const float4* cb = (const float4*)(codebook + (size_t)idx * 8);
    float4 lo = cb[0], hi = cb[1];
    size_t base = (size_t)g * 8 * K_DIM + i;
    Bt[base + 0 * K_DIM] = f2bf(lo.x);
    Bt[base + 1 * K_DIM] = f2bf(lo.y);
    Bt[base + 2 * K_DIM] = f2bf(lo.z);
    Bt[base + 3 * K_DIM] = f2bf(lo.w);
    Bt[base + 4 * K_DIM] = f2bf(hi.x);
    Bt[base + 5 * K_DIM] = f2bf(hi.y);
    Bt[base + 6 * K_DIM] = f2bf(hi.z);
    Bt[base + 7 * K_DIM] = f2bf(hi.w);
}

// ---- 8-phase 256x256 GEMM helpers ----
__device__ __forceinline__ void load_af4(const ushort_t* p, const int (&off)[4][2],
                                         short8 (&fr)[4][2]) {
#pragma unroll
    for (int i = 0; i < 4; ++i)
#pragma unroll
        for (int kk = 0; kk < 2; ++kk)
            fr[i][kk] = *(const short8*)((const char*)p + off[i][kk]);
}

__device__ __forceinline__ void load_bf2(const ushort_t* p, const int (&off)[2][2],
                                         short8 (&fr)[2][2]) {
#pragma unroll
    for (int j = 0; j < 2; ++j)
#pragma unroll
        for (int kk = 0; kk < 2; ++kk)
            fr[j][kk] = *(const short8*)((const char*)p + off[j][kk]);
}

__device__ __forceinline__ void mfma16(const short8 (&af)[4][2], const short8 (&bf)[2][2],
                                       f32x4 (&acc)[8][4], int I0, int J0) {
    __builtin_amdgcn_s_setprio(1);
#pragma unroll
    for (int kk = 0; kk < 2; ++kk)
#pragma unroll
        for (int i = 0; i < 4; ++i)
#pragma unroll
            for (int j = 0; j < 2; ++j)
                acc[I0 + i][J0 + j] = __builtin_amdgcn_mfma_f32_16x16x32_bf16(
                    af[i][kk], bf[j][kk], acc[I0 + i][J0 + j], 0, 0, 0);
    __builtin_amdgcn_s_setprio(0);
}

// ---- kernel 3: C = A(MxK) * Bt(NxK)^T + bias ; 256^2 tile, 8-phase schedule ----
// Identical to R3 except the block->tile mapping: 2D XCD-rectangle swizzle.
__global__ __launch_bounds__(512, 2) void gemm_256_8phase(const ushort_t* __restrict__ A,
                                                          const ushort_t* __restrict__ Bt,
                                                          const float* __restrict__ bias,
                                                          float* __restrict__ C) {
    __shared__ __align__(16) ushort_t lds_a[2][2][128 * 64];
    __shared__ __align__(16) ushort_t lds_b[2][2][128 * 64];

    // 2D XCD swizzle: each XCD's concurrent 32 blocks form a 4(m) x 8(n)
    // rectangle; chip-wide window = 16x16 tile quadrant (32 MB A+B) instead of
    // 4 m-stripes x full N (264 MB). Bijective: bid<->(x,q), (x,q)<->(mt,nt).
    const int bid = blockIdx.x;                  // 0..1023
    const int x = bid & 7;                       // XCD
    const int q = bid >> 3;                      // 0..127
    const int mt = ((x >> 1) << 2) + (q & 3) + (((q >> 5) & 1) << 4);
    const int nt = ((x & 1) << 3) + ((q >> 2) & 7) + (((q >> 6) & 1) << 4);
    const int m0 = mt * BM;
    const int n0 = nt * BN;

    const int tid = threadIdx.x;
    const int lane = tid & 63;
    const int wid = tid >> 6;              // 0..7
    const int wm = wid >> 2, wn = wid & 3; // 2 x 4 wave grid
    const int lane15 = lane & 15, laneq = lane >> 4;

    // --- staging addresses: linear LDS dest granule G -> inverse-swizzled global col ---
    const int G0 = tid, G1 = 512 + tid;
    const int r0 = G0 >> 3, r1 = G1 >> 3;                 // half-tile row 0..127
    const int c0 = (G0 & 7) ^ (r0 & 7), c1 = (G1 & 7) ^ (r1 & 7);
    const size_t aoff0 = (size_t)(m0 + r0) * K_DIM + c0 * 8;
    const size_t aoff1 = (size_t)(m0 + r1) * K_DIM + c1 * 8;
    const size_t boff0 = (size_t)(n0 + r0) * K_DIM + c0 * 8;
    const size_t boff1 = (size_t)(n0 + r1) * K_DIM + c1 * 8;
    const int dq0 = G0 * 16, dq1 = G1 * 16;               // LDS byte offset in half
    const size_t HOFF = (size_t)128 * K_DIM;              // global row offset of half 1

#define STAGE_A(gt, hh) do { \
        char* _d = (char*)&lds_a[(gt) & 1][hh][0]; \
        async_copy16(A + aoff0 + (size_t)(hh) * HOFF + (size_t)(gt) * BK, _d + dq0); \
        async_copy16(A + aoff1 + (size_t)(hh) * HOFF + (size_t)(gt) * BK, _d + dq1); \
    } while (0)
#define STAGE_B(gt, hh) do { \
        char* _d = (char*)&lds_b[(gt) & 1][hh][0]; \
        async_copy16(Bt + boff0 + (size_t)(hh) * HOFF + (size_t)(gt) * BK, _d + dq0); \
        async_copy16(Bt + boff1 + (size_t)(hh) * HOFF + (size_t)(gt) * BK, _d + dq1); \
    } while (0)

    // --- swizzled ds_read byte offsets (within a [128][64] half) ---
    int offA[4][2], offB[2][2];
#pragma unroll
    for (int i = 0; i < 4; ++i) {
        int row = wm * 64 + i * 16 + lane15;
#pragma unroll
        for (int kk = 0; kk < 2; ++kk)
            offA[i][kk] = row * 128 + (((kk * 4 + laneq) ^ (row & 7)) * 16);
    }
#pragma unroll
    for (int j = 0; j < 2; ++j) {
        int row = wn * 32 + j * 16 + lane15;
#pragma unroll
        for (int kk = 0; kk < 2; ++kk)
            offB[j][kk] = row * 128 + (((kk * 4 + laneq) ^ (row & 7)) * 16);
    }

    f32x4 acc[8][4];
#pragma unroll
    for (int i = 0; i < 8; ++i)
#pragma unroll
        for (int j = 0; j < 4; ++j) acc[i][j] = (f32x4){0.f, 0.f, 0.f, 0.f};

    // --- prologue: tile0 fully + {Bh0,Ah1,Bh1} of tile1 (7 half-tiles, 14 loads) ---
    STAGE_A(0, 0); STAGE_B(0, 0); STAGE_A(0, 1); STAGE_B(0, 1);
    STAGE_B(1, 0); STAGE_A(1, 1); STAGE_B(1, 1);
    asm volatile("s_waitcnt vmcnt(6)" ::: "memory");   // tile0 landed, 3 halves in flight
    BAR();

    short8 af[4][2], bf[2][2];

    for (int g = 0; g < NT; ++g) {
        const int d = g & 1;
        // P1: (m-half 0, n-half 0) — 12 ds_reads; stage Ah0(g+1)
        load_af4(&lds_a[d][0][0], offA, af);
        load_bf2(&lds_b[d][0][0], offB, bf);
        if (g + 1 < NT) STAGE_A(g + 1, 0);
        asm volatile("s_waitcnt lgkmcnt(8)" ::: "memory");
        BAR(); LGKM0();
        mfma16(af, bf, acc, 0, 0);
        BAR();
        // P2: (m-half 1, n-half 0) — reuse bf; stage Bh0(g+2) into freed slot
        load_af4(&lds_a[d][1][0], offA, af);
        if (g + 2 < NT) STAGE_B(g + 2, 0);
        BAR(); LGKM0();
        mfma16(af, bf, acc, 4, 0);
        BAR();
        // P3: (m-half 1, n-half 1) — reuse af; stage Ah1(g+2)
        load_bf2(&lds_b[d][1][0], offB, bf);
        if (g + 2 < NT) STAGE_A(g + 2, 1);
        BAR(); LGKM0();
        mfma16(af, bf, acc, 4, 2);
        BAR();
        // P4: (m-half 0, n-half 1) — reuse bf; stage Bh1(g+2); counted vmcnt
        load_af4(&lds_a[d][0][0], offA, af);
        if (g + 2 < NT) STAGE_B(g + 2, 1);
        BAR(); LGKM0();
        mfma16(af, bf, acc, 0, 2);
        if (g < NT - 2)       { asm volatile("s_waitcnt vmcnt(6)" ::: "memory"); }
        else if (g == NT - 2) { asm volatile("s_waitcnt vmcnt(0)" ::: "memory"); }
        BAR();
    }

    // --- epilogue: bias + f32 store ---
#pragma unroll
    for (int ig = 0; ig < 8; ++ig) {
        int row = m0 + (ig >> 2) * 128 + wm * 64 + (ig & 3) * 16 + laneq * 4;
#pragma unroll
        for (int jg = 0; jg < 4; ++jg) {
            int col = n0 + (jg >> 1) * 128 + wn * 32 + (jg & 1) * 16 + lane15;
            float bv = bias[col];
            f32x4 v = acc[ig][jg];
#pragma unroll
            for (int q2 = 0; q2 < 4; ++q2)
                C[(size_t)(row + q2) * N_DIM + col] = v[q2] + bv;
        }
    }
#undef STAGE_A
#undef STAGE_B
}

extern "C" void kernel_launch(void* const* d_in, const int* in_sizes, int n_in,
                              void* d_out, int out_size, void* d_ws, size_t ws_size,
                              hipStream_t stream) {
    const float* x = (const float*)d_in[0];
    const float* codebook = (const float*)d_in[1];
    const int* indices = (const int*)d_in[2];      // harness: integer -> int32
    const float* bias = (const float*)d_in[3];
    float* out = (float*)d_out;

    ushort_t* A  = (ushort_t*)d_ws;                               // 32 MB
    ushort_t* Bt = (ushort_t*)d_ws + (size_t)M_DIM * K_DIM;       // 32 MB

    convert_x<<<dim3(M_DIM * K_DIM / (256 * 8)), 256, 0, stream>>>(x, A);
    dequant_wt<<<dim3(1024, 8), 256, 0, stream>>>(indices, codebook, Bt);
    gemm_256_8phase<<<dim3((M_DIM / BM) * (N_DIM / BN)), 512, 0, stream>>>(A, Bt, bias, out);
}

// Round 6
// 301.911 us; speedup vs baseline: 1.3235x; 1.0922x over previous
//
#include <hip/hip_runtime.h>
#include <hip/hip_bf16.h>

typedef unsigned short ushort_t;
typedef __attribute__((ext_vector_type(8))) short short8;
typedef __attribute__((ext_vector_type(4))) float f32x4;

#define M_DIM 8192
#define N_DIM 8192
#define K_DIM 2048
#define BM 256
#define BN 256
#define BK 64
#define NT (K_DIM / BK)   // 32 K-tiles

__device__ __forceinline__ ushort_t f2bf(float f) {
    union { float f; unsigned u; } v; v.f = f;
    unsigned r = v.u + 0x7fffu + ((v.u >> 16) & 1u);   // RNE
    return (ushort_t)(r >> 16);
}

__device__ __forceinline__ void async_copy16(const void* g, void* l) {
    __builtin_amdgcn_global_load_lds(
        (const __attribute__((address_space(1))) void*)g,
        (__attribute__((address_space(3))) void*)l, 16, 0, 0);
}

#define BAR() __builtin_amdgcn_s_barrier()
#define LGKM0() do { asm volatile("s_waitcnt lgkmcnt(0)" ::: "memory"); \
                     __builtin_amdgcn_sched_barrier(0); } while (0)

// ---- kernel 1: x (f32) -> A (bf16) ----
__global__ __launch_bounds__(256) void convert_x(const float* __restrict__ x,
                                                 ushort_t* __restrict__ A) {
    int t = blockIdx.x * 256 + threadIdx.x;
    const float4* p = (const float4*)x + (size_t)t * 2;
    float4 a = p[0], b = p[1];
    short8 o;
    o[0] = (short)f2bf(a.x); o[1] = (short)f2bf(a.y);
    o[2] = (short)f2bf(a.z); o[3] = (short)f2bf(a.w);
    o[4] = (short)f2bf(b.x); o[5] = (short)f2bf(b.y);
    o[6] = (short)f2bf(b.z); o[7] = (short)f2bf(b.w);
    *(short8*)(A + (size_t)t * 8) = o;
}

// ---- kernel 2: codebook gather -> Bt (bf16, N x K layout) ----
__global__ __launch_bounds__(256) void dequant_wt(const int* __restrict__ indices,
                                                  const float* __restrict__ codebook,
                                                  ushort_t* __restrict__ Bt) {
    int g = blockIdx.x;                       // column group 0..1023
    int i = blockIdx.y * 256 + threadIdx.x;   // K row 0..2047
    int idx = indices[(size_t)i * 1024 + g];
    const float4* cb = (const float4*)(codebook + (size_t)idx * 8);
    float4 lo = cb[0], hi = cb[1];
    size_t base = (size_t)g * 8 * K_DIM + i;
    Bt[base + 0 * K_DIM] = f2bf(lo.x);
    Bt[base + 1 * K_DIM] = f2bf(lo.y);
    Bt[base + 2 * K_DIM] = f2bf(lo.z);
    Bt[base + 3 * K_DIM] = f2bf(lo.w);
    Bt[base + 4 * K_DIM] = f2bf(hi.x);
    Bt[base + 5 * K_DIM] = f2bf(hi.y);
    Bt[base + 6 * K_DIM] = f2bf(hi.z);
    Bt[base + 7 * K_DIM] = f2bf(hi.w);
}

// ---- 8-phase 256x256 GEMM helpers ----
__device__ __forceinline__ void load_af4(const ushort_t* p, const int (&off)[4][2],
                                         short8 (&fr)[4][2]) {
#pragma unroll
    for (int i = 0; i < 4; ++i)
#pragma unroll
        for (int kk = 0; kk < 2; ++kk)
            fr[i][kk] = *(const short8*)((const char*)p + off[i][kk]);
}

__device__ __forceinline__ void load_bf2(const ushort_t* p, const int (&off)[2][2],
                                         short8 (&fr)[2][2]) {
#pragma unroll
    for (int j = 0; j < 2; ++j)
#pragma unroll
        for (int kk = 0; kk < 2; ++kk)
            fr[j][kk] = *(const short8*)((const char*)p + off[j][kk]);
}

__device__ __forceinline__ void mfma16(const short8 (&af)[4][2], const short8 (&bf)[2][2],
                                       f32x4 (&acc)[8][4], int I0, int J0) {
    __builtin_amdgcn_s_setprio(1);
#pragma unroll
    for (int kk = 0; kk < 2; ++kk)
#pragma unroll
        for (int i = 0; i < 4; ++i)
#pragma unroll
            for (int j = 0; j < 2; ++j)
                acc[I0 + i][J0 + j] = __builtin_amdgcn_mfma_f32_16x16x32_bf16(
                    af[i][kk], bf[j][kk], acc[I0 + i][J0 + j], 0, 0, 0);
    __builtin_amdgcn_s_setprio(0);
}

// ---- kernel 3: C = A(MxK) * Bt(NxK)^T + bias ; 256^2 tile, 8-phase schedule ----
// R6: minimum-read phases (12,4,8,0) — hold both B half-fragment sets across
// the K-tile; quadrant order (m0n0),(m0n1),(m1n1),(m1n0).
__global__ __launch_bounds__(512, 2) void gemm_256_8phase(const ushort_t* __restrict__ A,
                                                          const ushort_t* __restrict__ Bt,
                                                          const float* __restrict__ bias,
                                                          float* __restrict__ C) {
    __shared__ __align__(16) ushort_t lds_a[2][2][128 * 64];
    __shared__ __align__(16) ushort_t lds_b[2][2][128 * 64];

    // 2D XCD-rectangle swizzle (kept from R5: FETCH 542->197 MB)
    const int bid = blockIdx.x;                  // 0..1023
    const int x = bid & 7;                       // XCD
    const int q = bid >> 3;                      // 0..127
    const int mt = ((x >> 1) << 2) + (q & 3) + (((q >> 5) & 1) << 4);
    const int nt = ((x & 1) << 3) + ((q >> 2) & 7) + (((q >> 6) & 1) << 4);
    const int m0 = mt * BM;
    const int n0 = nt * BN;

    const int tid = threadIdx.x;
    const int lane = tid & 63;
    const int wid = tid >> 6;              // 0..7
    const int wm = wid >> 2, wn = wid & 3; // 2 x 4 wave grid
    const int lane15 = lane & 15, laneq = lane >> 4;

    // --- staging addresses: linear LDS dest granule G -> inverse-swizzled global col ---
    const int G0 = tid, G1 = 512 + tid;
    const int r0 = G0 >> 3, r1 = G1 >> 3;                 // half-tile row 0..127
    const int c0 = (G0 & 7) ^ (r0 & 7), c1 = (G1 & 7) ^ (r1 & 7);
    const size_t aoff0 = (size_t)(m0 + r0) * K_DIM + c0 * 8;
    const size_t aoff1 = (size_t)(m0 + r1) * K_DIM + c1 * 8;
    const size_t boff0 = (size_t)(n0 + r0) * K_DIM + c0 * 8;
    const size_t boff1 = (size_t)(n0 + r1) * K_DIM + c1 * 8;
    const int dq0 = G0 * 16, dq1 = G1 * 16;               // LDS byte offset in half
    const size_t HOFF = (size_t)128 * K_DIM;              // global row offset of half 1

#define STAGE_A(gt, hh) do { \
        char* _d = (char*)&lds_a[(gt) & 1][hh][0]; \
        async_copy16(A + aoff0 + (size_t)(hh) * HOFF + (size_t)(gt) * BK, _d + dq0); \
        async_copy16(A + aoff1 + (size_t)(hh) * HOFF + (size_t)(gt) * BK, _d + dq1); \
    } while (0)
#define STAGE_B(gt, hh) do { \
        char* _d = (char*)&lds_b[(gt) & 1][hh][0]; \
        async_copy16(Bt + boff0 + (size_t)(hh) * HOFF + (size_t)(gt) * BK, _d + dq0); \
        async_copy16(Bt + boff1 + (size_t)(hh) * HOFF + (size_t)(gt) * BK, _d + dq1); \
    } while (0)

    // --- swizzled ds_read byte offsets (within a [128][64] half) ---
    int offA[4][2], offB[2][2];
#pragma unroll
    for (int i = 0; i < 4; ++i) {
        int row = wm * 64 + i * 16 + lane15;
#pragma unroll
        for (int kk = 0; kk < 2; ++kk)
            offA[i][kk] = row * 128 + (((kk * 4 + laneq) ^ (row & 7)) * 16);
    }
#pragma unroll
    for (int j = 0; j < 2; ++j) {
        int row = wn * 32 + j * 16 + lane15;
#pragma unroll
        for (int kk = 0; kk < 2; ++kk)
            offB[j][kk] = row * 128 + (((kk * 4 + laneq) ^ (row & 7)) * 16);
    }

    f32x4 acc[8][4];
#pragma unroll
    for (int i = 0; i < 8; ++i)
#pragma unroll
        for (int j = 0; j < 4; ++j) acc[i][j] = (f32x4){0.f, 0.f, 0.f, 0.f};

    // --- prologue: tile0 fully + {Bh0(1),Bh1(1),Ah1(1)} (7 half-tiles, 14 loads) ---
    // matches steady-state in-flight pattern: entering iter g, outstanding =
    // stages of P2..P4 of iter g-1 = {B(g+1,0), B(g+1,1), A(g+1,1)}.
    STAGE_A(0, 0); STAGE_B(0, 0); STAGE_B(0, 1); STAGE_A(0, 1);
    STAGE_B(1, 0); STAGE_B(1, 1); STAGE_A(1, 1);
    asm volatile("s_waitcnt vmcnt(6)" ::: "memory");   // tile0 landed
    BAR();

    short8 af[4][2], bf0[2][2], bf1[2][2];

    for (int g = 0; g < NT; ++g) {
        const int d = g & 1;
        // P1: (m0,n0) — reads A0(8) + B0(4); stage Ah0(g+1) (writes [1-d][0], safe)
        load_af4(&lds_a[d][0][0], offA, af);
        load_bf2(&lds_b[d][0][0], offB, bf0);
        if (g + 1 < NT) STAGE_A(g + 1, 0);
        asm volatile("s_waitcnt lgkmcnt(8)" ::: "memory");
        BAR(); LGKM0();
        mfma16(af, bf0, acc, 0, 0);
        BAR();
        // P2: (m0,n1) — reads B1(4), af held; stage Bh0(g+2) (B0 read done at P1 bar)
        load_bf2(&lds_b[d][1][0], offB, bf1);
        if (g + 2 < NT) STAGE_B(g + 2, 0);
        BAR(); LGKM0();
        mfma16(af, bf1, acc, 0, 2);
        BAR();
        // P3: (m1,n1) — reads A1(8), bf1 held; stage Bh1(g+2) (B1 read done at P2 bar)
        load_af4(&lds_a[d][1][0], offA, af);
        if (g + 2 < NT) STAGE_B(g + 2, 1);
        BAR(); LGKM0();
        mfma16(af, bf1, acc, 4, 2);
        BAR();
        // P4: (m1,n0) — ZERO reads: af(A1) + bf0 held; stage Ah1(g+2); counted vmcnt
        if (g + 2 < NT) STAGE_A(g + 2, 1);
        BAR(); LGKM0();
        mfma16(af, bf0, acc, 4, 0);
        if (g < NT - 2) { asm volatile("s_waitcnt vmcnt(6)" ::: "memory"); }
        else            { asm volatile("s_waitcnt vmcnt(0)" ::: "memory"); }
        BAR();
    }

    // --- epilogue: bias + f32 store ---
#pragma unroll
    for (int ig = 0; ig < 8; ++ig) {
        int row = m0 + (ig >> 2) * 128 + wm * 64 + (ig & 3) * 16 + laneq * 4;
#pragma unroll
        for (int jg = 0; jg < 4; ++jg) {
            int col = n0 + (jg >> 1) * 128 + wn * 32 + (jg & 1) * 16 + lane15;
            float bv = bias[col];
            f32x4 v = acc[ig][jg];
#pragma unroll
            for (int q2 = 0; q2 < 4; ++q2)
                C[(size_t)(row + q2) * N_DIM + col] = v[q2] + bv;
        }
    }
#undef STAGE_A
#undef STAGE_B
}

extern "C" void kernel_launch(void* const* d_in, const int* in_sizes, int n_in,
                              void* d_out, int out_size, void* d_ws, size_t ws_size,
                              hipStream_t stream) {
    const float* x = (const float*)d_in[0];
    const float* codebook = (const float*)d_in[1];
    const int* indices = (const int*)d_in[2];      // harness: integer -> int32
    const float* bias = (const float*)d_in[3];
    float* out = (float*)d_out;

    ushort_t* A  = (ushort_t*)d_ws;                               // 32 MB
    ushort_t* Bt = (ushort_t*)d_ws + (size_t)M_DIM * K_DIM;       // 32 MB

    convert_x<<<dim3(M_DIM * K_DIM / (256 * 8)), 256, 0, stream>>>(x, A);
    dequant_wt<<<dim3(1024, 8), 256, 0, stream>>>(indices, codebook, Bt);
    gemm_256_8phase<<<dim3((M_DIM / BM) * (N_DIM / BN)), 512, 0, stream>>>(A, Bt, bias, out);
}